// Round 7
// baseline (53915.619 us; speedup 1.0000x reference)
//
#include <hip/hip_runtime.h>
#include <hip/hip_bf16.h>

// LSTM_19267223290530 — 2-layer LSTM (B=64,T=1024,IN=128,HID=512) + FC.
// Round 7: layer-concurrent single launch (1024 serial ticks), ONE chain per
// wg (R6's dual-chain juggling removed — it serialized waits and blew VGPRs).
// 256 wgs = 2 layers x 2 groups(32 batches) x 64 wgs(8 units).
// Per step: poll flags -> stage x -> x-part (w_ih streamed from L2) ->
// stage h -> h-part (w_hh in LDS) -> reduce -> gates -> store -> flag.
// All cross-wg data via relaxed agent atomics (no L2 maintenance, R4-proven).

#define NTH 256
#define HIDDEN 512
#define TSTEPS 1024
#define SPIN_LIMIT 400000000ull   // ~4s bail-out: fail visibly, never hang

using bf16 = __hip_bfloat16;

__device__ __forceinline__ float b2f(unsigned short s) {
  return __uint_as_float(((unsigned)s) << 16);
}
__device__ __forceinline__ float sigm(float x) { return 1.0f / (1.0f + __expf(-x)); }
__device__ __forceinline__ float tanh_fast(float x) {
  float ax = fabsf(x);
  float e2 = __expf(2.0f * ax);
  float t  = 1.0f - 2.0f / (e2 + 1.0f);
  return copysignf(t, x);
}
__device__ __forceinline__ void fma4(float& a, const float4 w, const float4 h) {
  a = fmaf(w.x, h.x, a); a = fmaf(w.y, h.y, a);
  a = fmaf(w.z, h.z, a); a = fmaf(w.w, h.w, a);
}
__device__ __forceinline__ void st_cc(float* p, float v) {
  __hip_atomic_store(p, v, __ATOMIC_RELAXED, __HIP_MEMORY_SCOPE_AGENT);
}
__device__ __forceinline__ float ld_cc(const float* p) {
  return __hip_atomic_load((float*)p, __ATOMIC_RELAXED, __HIP_MEMORY_SCOPE_AGENT);
}
__device__ __forceinline__ void st_cu(unsigned* p, unsigned v) {
  __hip_atomic_store(p, v, __ATOMIC_RELAXED, __HIP_MEMORY_SCOPE_AGENT);
}
__device__ __forceinline__ unsigned ld_cu(const unsigned* p) {
  return __hip_atomic_load((unsigned*)p, __ATOMIC_RELAXED, __HIP_MEMORY_SCOPE_AGENT);
}
__device__ __forceinline__ void st_ci(int* p, int v) {
  __hip_atomic_store(p, v, __ATOMIC_RELAXED, __HIP_MEMORY_SCOPE_AGENT);
}
__device__ __forceinline__ int ld_ci(const int* p) {
  return __hip_atomic_load((int*)p, __ATOMIC_RELAXED, __HIP_MEMORY_SCOPE_AGENT);
}
__device__ __forceinline__ void cfence() { asm volatile("" ::: "memory"); }

// LDS stage swizzle: key=(b>>1)&7 -> 2-way worst on h-part reads (free, m136).
__device__ __forceinline__ int swz(int b, int c) {
  return b * 512 + ((((c >> 2) ^ ((b >> 1) & 7)) << 2) | (c & 3));
}

// ---------------------------------------------------------------------------
// grid 256 x 256 thr (1 wg/CU): bid>>7 = L, (bid>>6)&1 = g, bid&63 = w.
// wg covers units [8w,8w+8) x batches [32g,32g+32), one chain of 1024 steps.
// threads: rr=tid&7 (4-row quad), bb=(tid>>3)&7 (4-batch quad), kc=tid>>6
// (K-chunk 128 cols). L1 step t waits L0 flags >= t+1 (seq[t] ready).
// ---------------------------------------------------------------------------
template<int SEQF32>
__global__ __launch_bounds__(NTH, 1)
void lstm2(const float* __restrict__ xin,
           const float* __restrict__ wih0, const float* __restrict__ whh0,
           const float* __restrict__ bih0, const float* __restrict__ bhh0,
           const float* __restrict__ wih1, const float* __restrict__ whh1,
           const float* __restrict__ bih1, const float* __restrict__ bhh1,
           float* __restrict__ hbuf1,   // [2g][2buf][32][512]  (L1 only)
           void* __restrict__ seqv,     // f32 [64][1024][512] | u32 [64][1024][256]
           int* __restrict__ bars)      // flags: chain (L*2+g) at bars+chain*64
{
  const int tid = threadIdx.x, bid = blockIdx.x;
  const int L = bid >> 7, g = (bid >> 6) & 1, w = bid & 63;
  const int u0 = w * 8, b0 = g * 32;
  const float* w_ih = L ? wih1 : wih0;
  const float* w_hh = L ? whh1 : whh0;
  const float* bi   = L ? bih1 : bih0;
  const float* bh   = L ? bhh1 : bhh0;
  const int DIN = L ? 512 : 128;

  float*    seqf = (float*)seqv;
  unsigned* sequ = (unsigned*)seqv;

  extern __shared__ float lds[];
  float4* wv4  = (float4*)lds;            // [32][128] w_hh slice, swizzled
  float*  hst  = lds + 4 * 32 * 128;      // 16384 f: x/h stage, then red+gbuf
  float4* hst4 = (float4*)hst;
  float*  red  = hst;                     // [4][32 r *33 + b] overlay
  float*  gbuf = hst + 4224;              // [32 r *33 + b]
  float*  bsum = hst + 16384;             // [32]

  for (int idx = tid; idx < 32 * 128; idx += NTH) {
    int r = idx >> 7, c4 = idx & 127;
    int grow = (r >> 3) * HIDDEN + u0 + (r & 7);
    wv4[r * 128 + (c4 ^ ((r >> 2) & 7))] =
        *(const float4*)(w_hh + (size_t)grow * HIDDEN + c4 * 4);
  }
  if (tid < 32) {
    int grow = (tid >> 3) * HIDDEN + u0 + (tid & 7);
    bsum[tid] = bi[grow] + bh[grow];
  }
  const int rr = tid & 7, bb = (tid >> 3) & 7, kc = tid >> 6;
  const float* wxg[4];
#pragma unroll
  for (int j = 0; j < 4; ++j) {
    int r = 4 * rr + j;
    int grow = (r >> 3) * HIDDEN + u0 + (r & 7);
    wxg[j] = w_ih + (size_t)grow * DIN;
  }
  int* fl  = bars + (L * 2 + g) * 64;   // own chain flags
  int* fl0 = bars + g * 64;             // layer-0 chain, same batches
  float* hb = hbuf1 + (size_t)g * 2 * 32 * HIDDEN;

  float creg = 0.0f;                    // c-state: thread owns (bl=tid>>3, lu=tid&7)
  const int blf = tid >> 3, luf = tid & 7;
  __syncthreads();

  for (int t = 0; t < TSTEPS; ++t) {
    // ---- L0: prefetch x[t] into regs (input, barrier-independent) ----
    float4 xr[4];
    if (L == 0) {
#pragma unroll
      for (int n = 0; n < 4; ++n) {
        int idx = tid + n * NTH, b = idx >> 5, c4 = idx & 31;
        xr[n] = *(const float4*)(xin + ((size_t)(b0 + b) * TSTEPS + t) * 128 + c4 * 4);
      }
    }
    // ---- one-hop barrier: 64 lanes poll 64 flags (+ L0 flags for L1) ----
    if (tid < 64) {
      unsigned long long sp0 = __builtin_amdgcn_s_memrealtime();
      while (true) {
        bool ok = ld_ci(&fl[tid]) >= t;
        if (L == 1) ok = ok && (ld_ci(&fl0[tid]) >= t + 1);
        if (__all(ok)) break;
        if (__builtin_amdgcn_s_memrealtime() - sp0 > SPIN_LIMIT) break;
        __builtin_amdgcn_s_sleep(1);
      }
      cfence();
    }
    __syncthreads();

    // ---- stage x into hst ----
    if (L == 0) {
#pragma unroll
      for (int n = 0; n < 4; ++n) {
        int idx = tid + n * NTH, b = idx >> 5, c4 = idx & 31;
        hst4[b * 32 + (c4 ^ ((b >> 1) & 7))] = xr[n];
      }
    } else if (SEQF32) {
#pragma unroll 32
      for (int n = 0; n < 64; ++n) {
        int idx = tid + n * NTH, b = idx >> 9, c = idx & 511;
        float v = ld_cc(seqf + ((size_t)(b0 + b) * TSTEPS + t) * HIDDEN + c);
        hst[swz(b, c)] = v;
      }
    } else {
#pragma unroll 16
      for (int n = 0; n < 32; ++n) {
        int idx = tid + n * NTH, b = idx >> 8, wi = idx & 255;
        unsigned v = ld_cu(sequ + ((size_t)(b0 + b) * TSTEPS + t) * 256 + wi);
        int c0 = wi * 2, base = swz(b, c0);
        hst[base] = b2f((unsigned short)v);
        hst[base + 1] = b2f((unsigned short)(v >> 16));
      }
    }
    __syncthreads();

    float acc[4][4];
#pragma unroll
    for (int j = 0; j < 4; ++j)
#pragma unroll
      for (int i = 0; i < 4; ++i) acc[j][i] = 0.0f;

    // ---- x-part: K = DIN, weights streamed from L2 ----
    if (L == 0) {
#pragma unroll
      for (int kk = 0; kk < 8; ++kk) {
        int k4 = kc * 8 + kk;
        float4 wq[4], xq[4];
#pragma unroll
        for (int j = 0; j < 4; ++j) wq[j] = *(const float4*)(wxg[j] + k4 * 4);
#pragma unroll
        for (int i = 0; i < 4; ++i) {
          int b = 4 * bb + i;
          xq[i] = hst4[b * 32 + (k4 ^ ((b >> 1) & 7))];
        }
#pragma unroll
        for (int j = 0; j < 4; ++j)
#pragma unroll
          for (int i = 0; i < 4; ++i) fma4(acc[j][i], wq[j], xq[i]);
      }
    } else {
#pragma unroll 4
      for (int kk = 0; kk < 32; ++kk) {
        int k4 = kc * 32 + kk;
        float4 wq[4], xq[4];
#pragma unroll
        for (int j = 0; j < 4; ++j) wq[j] = *(const float4*)(wxg[j] + k4 * 4);
#pragma unroll
        for (int i = 0; i < 4; ++i) {
          int b = 4 * bb + i;
          xq[i] = hst4[b * 128 + (k4 ^ ((b >> 1) & 7))];
        }
#pragma unroll
        for (int j = 0; j < 4; ++j)
#pragma unroll
          for (int i = 0; i < 4; ++i) fma4(acc[j][i], wq[j], xq[i]);
      }
    }
    __syncthreads();   // x reads done before h overwrites stage

    // ---- stage h(t-1) into hst (L0: from seq; L1: from hbuf) ----
    if (t == 0) {
#pragma unroll
      for (int n = 0; n < 64; ++n) hst[tid + n * NTH] = 0.0f;
    } else if (L == 0) {
      if (SEQF32) {
#pragma unroll 32
        for (int n = 0; n < 64; ++n) {
          int idx = tid + n * NTH, b = idx >> 9, c = idx & 511;
          float v = ld_cc(seqf + ((size_t)(b0 + b) * TSTEPS + (t - 1)) * HIDDEN + c);
          hst[swz(b, c)] = v;
        }
      } else {
#pragma unroll 16
        for (int n = 0; n < 32; ++n) {
          int idx = tid + n * NTH, b = idx >> 8, wi = idx & 255;
          unsigned v = ld_cu(sequ + ((size_t)(b0 + b) * TSTEPS + (t - 1)) * 256 + wi);
          int c0 = wi * 2, base = swz(b, c0);
          hst[base] = b2f((unsigned short)v);
          hst[base + 1] = b2f((unsigned short)(v >> 16));
        }
      }
    } else {
      const float* hsrc = hb + (size_t)(t & 1) * (32 * HIDDEN);
#pragma unroll 32
      for (int n = 0; n < 64; ++n) {
        int idx = tid + n * NTH, b = idx >> 9, c = idx & 511;
        float v = ld_cc(hsrc + b * HIDDEN + c);
        hst[swz(b, c)] = v;
      }
    }
    __syncthreads();

    // ---- h-part: K = 512, w_hh from LDS ----
#pragma unroll 4
    for (int kk = 0; kk < 32; ++kk) {
      int k4 = kc * 32 + kk;
      float4 wq[4], hq[4];
#pragma unroll
      for (int j = 0; j < 4; ++j) wq[j] = wv4[(4 * rr + j) * 128 + (k4 ^ rr)];
#pragma unroll
      for (int i = 0; i < 4; ++i) {
        int b = 4 * bb + i;
        hq[i] = hst4[b * 128 + (k4 ^ ((b >> 1) & 7))];
      }
#pragma unroll
      for (int j = 0; j < 4; ++j)
#pragma unroll
        for (int i = 0; i < 4; ++i) fma4(acc[j][i], wq[j], hq[i]);
    }
    __syncthreads();   // h reads done before reduction overlay

    // ---- K-split reduction (4 partials) ----
#pragma unroll
    for (int j = 0; j < 4; ++j)
#pragma unroll
      for (int i = 0; i < 4; ++i)
        red[kc * 1056 + (4 * rr + j) * 33 + (4 * bb + i)] = acc[j][i];
    __syncthreads();
#pragma unroll
    for (int q = 0; q < 4; ++q) {
      int idx = tid + q * NTH, r = idx >> 5, b = idx & 31;
      float s = bsum[r];
#pragma unroll
      for (int k2 = 0; k2 < 4; ++k2) s += red[k2 * 1056 + r * 33 + b];
      gbuf[r * 33 + b] = s;
    }
    __syncthreads();

    // ---- gates: thread owns (blf, luf) ----
    {
      float gi = gbuf[(0  + luf) * 33 + blf];
      float gf = gbuf[(8  + luf) * 33 + blf];
      float gg = gbuf[(16 + luf) * 33 + blf];
      float go = gbuf[(24 + luf) * 33 + blf];
      float iv = sigm(gi), fv = sigm(gf), gv = tanh_fast(gg), ov = sigm(go);
      float c = fv * creg + iv * gv;
      creg = c;
      float hn = ov * tanh_fast(c);
      if (L == 0) {
        if (SEQF32) {
          st_cc(seqf + ((size_t)(b0 + blf) * TSTEPS + t) * HIDDEN + u0 + luf, hn);
        } else {
          float other = __shfl_xor(hn, 1);
          if ((luf & 1) == 0) {
            bf16 lo = __float2bfloat16(hn), hi = __float2bfloat16(other);
            unsigned pv = (unsigned)(*(unsigned short*)&lo) |
                          ((unsigned)(*(unsigned short*)&hi) << 16);
            st_cu(sequ + ((size_t)(b0 + blf) * TSTEPS + t) * 256 + ((u0 + luf) >> 1), pv);
          }
        }
      } else {
        st_cc(hb + (size_t)((t + 1) & 1) * (32 * HIDDEN) + blf * HIDDEN + u0 + luf, hn);
      }
    }
    __syncthreads();   // drains vmcnt: h stores visible before flag
    if (tid == 0) st_ci(&fl[w], t + 1);
  }
}

// ---------------------------------------------------------------------------
// FC: out[b][o] = dot(h2[b], fc_w[o]) + fc_b[o]. h2 = hbuf1[g][buf0][b&31].
// ---------------------------------------------------------------------------
__global__ __launch_bounds__(NTH, 1)
void fc_kernel(const float* __restrict__ hbuf1, const float* __restrict__ fcw,
               const float* __restrict__ fcb, float* __restrict__ out)
{
  extern __shared__ float lds[];
  float4* fw4 = (float4*)lds;          // [64][128] swizzled
  float4* h24 = fw4 + 64 * 128;        // [8][128]
  const int tid = threadIdx.x;
  const int bq  = blockIdx.x;

  for (int idx = tid; idx < 64 * 128; idx += NTH) {
    int o = idx >> 7, c4 = idx & 127;
    fw4[o * 128 + (c4 ^ (o & 7))] = *(const float4*)(fcw + (size_t)o * HIDDEN + c4 * 4);
  }
  for (int idx = tid; idx < 8 * 128; idx += NTH) {
    int b = idx >> 7, c4 = idx & 127;
    int bg = bq * 8 + b;
    const float* hp = hbuf1 + (size_t)(bg >> 5) * 2 * 32 * HIDDEN + (bg & 31) * HIDDEN;
    h24[b * 128 + c4] = *(const float4*)(hp + c4 * 4);
  }
  __syncthreads();

  const int o = tid & 63, bs = tid >> 6;
  float a0 = 0.f, a1 = 0.f;
  for (int c4 = 0; c4 < 128; ++c4) {
    float4 wv = fw4[o * 128 + (c4 ^ (o & 7))];
    float4 h0 = h24[(2 * bs) * 128 + c4];
    float4 h1 = h24[(2 * bs + 1) * 128 + c4];
    fma4(a0, wv, h0);
    fma4(a1, wv, h1);
  }
  const float bo = fcb[o];
  out[(size_t)(bq * 8 + 2 * bs) * 64 + o]     = a0 + bo;
  out[(size_t)(bq * 8 + 2 * bs + 1) * 64 + o] = a1 + bo;
}

__global__ void init_ws(float* hbuf1, int* bars)
{
  int i = blockIdx.x * blockDim.x + threadIdx.x;
  if (i < 2 * 2 * 32 * HIDDEN) hbuf1[i] = 0.0f;   // 65536 floats
  if (i < 1024) bars[i] = 0;
}

// ---------------------------------------------------------------------------
extern "C" void kernel_launch(void* const* d_in, const int* in_sizes, int n_in,
                              void* d_out, int out_size, void* d_ws, size_t ws_size,
                              hipStream_t stream)
{
  const float* x    = (const float*)d_in[0];
  const float* wih0 = (const float*)d_in[1];
  const float* whh0 = (const float*)d_in[2];
  const float* bih0 = (const float*)d_in[3];
  const float* bhh0 = (const float*)d_in[4];
  const float* wih1 = (const float*)d_in[5];
  const float* whh1 = (const float*)d_in[6];
  const float* bih1 = (const float*)d_in[7];
  const float* bhh1 = (const float*)d_in[8];
  const float* fcw  = (const float*)d_in[9];
  const float* fcb  = (const float*)d_in[10];
  float* out = (float*)d_out;

  // ws layout: bars 1024 int | hbuf1 65536 f | seq
  float* wsf   = (float*)d_ws;
  int*   bars  = (int*)d_ws;
  float* hbuf1 = wsf + 1024;
  void*  seqv  = (void*)(hbuf1 + 2 * 2 * 32 * HIDDEN);

  const size_t head_bytes = (size_t)(1024 + 65536) * 4;
  const size_t seq_f32    = (size_t)64 * TSTEPS * HIDDEN * 4;
  const bool f32seq = ws_size >= head_bytes + seq_f32;

  const size_t ldsS  = (size_t)(32 * 128) * 16 + (size_t)(16384 + 32) * 4;  // 131,200 B
  const size_t ldsfc = (size_t)(64 * 128 + 8 * 128) * 16;

  hipLaunchKernelGGL(init_ws, dim3(256), dim3(256), 0, stream, hbuf1, bars);

  if (f32seq) {
    auto* k = lstm2<1>;
    hipFuncSetAttribute((const void*)k, hipFuncAttributeMaxDynamicSharedMemorySize, (int)ldsS);
    void* args[] = { (void*)&x,
                     (void*)&wih0, (void*)&whh0, (void*)&bih0, (void*)&bhh0,
                     (void*)&wih1, (void*)&whh1, (void*)&bih1, (void*)&bhh1,
                     (void*)&hbuf1, (void*)&seqv, (void*)&bars };
    if (hipLaunchCooperativeKernel((const void*)k, dim3(256), dim3(NTH), args,
                                   (unsigned)ldsS, stream) != hipSuccess) {
      lstm2<1><<<dim3(256), dim3(NTH), ldsS, stream>>>(
          x, wih0, whh0, bih0, bhh0, wih1, whh1, bih1, bhh1, hbuf1, seqv, bars);
    }
  } else {
    auto* k = lstm2<0>;
    hipFuncSetAttribute((const void*)k, hipFuncAttributeMaxDynamicSharedMemorySize, (int)ldsS);
    void* args[] = { (void*)&x,
                     (void*)&wih0, (void*)&whh0, (void*)&bih0, (void*)&bhh0,
                     (void*)&wih1, (void*)&whh1, (void*)&bih1, (void*)&bhh1,
                     (void*)&hbuf1, (void*)&seqv, (void*)&bars };
    if (hipLaunchCooperativeKernel((const void*)k, dim3(256), dim3(NTH), args,
                                   (unsigned)ldsS, stream) != hipSuccess) {
      lstm2<0><<<dim3(256), dim3(NTH), ldsS, stream>>>(
          x, wih0, whh0, bih0, bhh0, wih1, whh1, bih1, bhh1, hbuf1, seqv, bars);
    }
  }

  hipFuncSetAttribute((const void*)fc_kernel, hipFuncAttributeMaxDynamicSharedMemorySize, (int)ldsfc);
  hipLaunchKernelGGL(fc_kernel, dim3(8), dim3(NTH), ldsfc, stream, hbuf1, fcw, fcb, out);
}

// Round 8
// 50634.564 us; speedup vs baseline: 1.0648x; 1.0648x over previous
//
#include <hip/hip_runtime.h>
#include <hip/hip_bf16.h>

// LSTM_19267223290530 — 2-layer LSTM (B=64,T=1024,IN=128,HID=512) + FC.
// Round 8: R7 layer-concurrent structure + R5's proven two-hop barrier.
// R7's regression was poll topology: 8K lanes polling 64 distinct coherent
// words melted the coherence point (83us/tick). Restored: flag stores ->
// single gatherer wg per chain -> one epoch word -> broadcast polls.
// Own-chain wait sandwiched after x-part (epoch hop hides under x compute).

#define NTH 256
#define HIDDEN 512
#define TSTEPS 1024
#define SPIN_LIMIT 400000000ull   // ~4s bail-out: fail visibly, never hang

using bf16 = __hip_bfloat16;

__device__ __forceinline__ float b2f(unsigned short s) {
  return __uint_as_float(((unsigned)s) << 16);
}
__device__ __forceinline__ float sigm(float x) { return 1.0f / (1.0f + __expf(-x)); }
__device__ __forceinline__ float tanh_fast(float x) {
  float ax = fabsf(x);
  float e2 = __expf(2.0f * ax);
  float t  = 1.0f - 2.0f / (e2 + 1.0f);
  return copysignf(t, x);
}
__device__ __forceinline__ void fma4(float& a, const float4 w, const float4 h) {
  a = fmaf(w.x, h.x, a); a = fmaf(w.y, h.y, a);
  a = fmaf(w.z, h.z, a); a = fmaf(w.w, h.w, a);
}
__device__ __forceinline__ void st_cc(float* p, float v) {
  __hip_atomic_store(p, v, __ATOMIC_RELAXED, __HIP_MEMORY_SCOPE_AGENT);
}
__device__ __forceinline__ float ld_cc(const float* p) {
  return __hip_atomic_load((float*)p, __ATOMIC_RELAXED, __HIP_MEMORY_SCOPE_AGENT);
}
__device__ __forceinline__ void st_cu(unsigned* p, unsigned v) {
  __hip_atomic_store(p, v, __ATOMIC_RELAXED, __HIP_MEMORY_SCOPE_AGENT);
}
__device__ __forceinline__ unsigned ld_cu(const unsigned* p) {
  return __hip_atomic_load((unsigned*)p, __ATOMIC_RELAXED, __HIP_MEMORY_SCOPE_AGENT);
}
__device__ __forceinline__ void st_ci(int* p, int v) {
  __hip_atomic_store(p, v, __ATOMIC_RELAXED, __HIP_MEMORY_SCOPE_AGENT);
}
__device__ __forceinline__ int ld_ci(const int* p) {
  return __hip_atomic_load((int*)p, __ATOMIC_RELAXED, __HIP_MEMORY_SCOPE_AGENT);
}
__device__ __forceinline__ void cfence() { asm volatile("" ::: "memory"); }

// LDS stage swizzle: key=(b>>1)&7 -> 2-way worst on h-part reads (free, m136).
__device__ __forceinline__ int swz(int b, int c) {
  return b * 512 + ((((c >> 2) ^ ((b >> 1) & 7)) << 2) | (c & 3));
}

// ---------------------------------------------------------------------------
// grid 256 x 256 thr (1 wg/CU): bid>>7 = L, (bid>>6)&1 = g, bid&63 = w.
// wg covers units [8w,8w+8) x batches [32g,32g+32), one chain of 1024 steps.
// Barrier: flags[chain*64+w] -> gatherer (w==0) -> ep[chain] single word.
// L1 step t additionally waits ep0 >= t+1 (seq[t] complete).
// ---------------------------------------------------------------------------
template<int SEQF32>
__global__ __launch_bounds__(NTH, 1)
void lstm2(const float* __restrict__ xin,
           const float* __restrict__ wih0, const float* __restrict__ whh0,
           const float* __restrict__ bih0, const float* __restrict__ bhh0,
           const float* __restrict__ wih1, const float* __restrict__ whh1,
           const float* __restrict__ bih1, const float* __restrict__ bhh1,
           float* __restrict__ hbuf1,   // [2g][2buf][32][512]  (L1 only)
           void* __restrict__ seqv,     // f32 [64][1024][512] | u32 [64][1024][256]
           int* __restrict__ bars)      // flags chain*64; epochs 512+chain*16
{
  const int tid = threadIdx.x, bid = blockIdx.x;
  const int L = bid >> 7, g = (bid >> 6) & 1, w = bid & 63;
  const int u0 = w * 8, b0 = g * 32;
  const float* w_ih = L ? wih1 : wih0;
  const float* w_hh = L ? whh1 : whh0;
  const float* bi   = L ? bih1 : bih0;
  const float* bh   = L ? bhh1 : bhh0;
  const int DIN = L ? 512 : 128;

  float*    seqf = (float*)seqv;
  unsigned* sequ = (unsigned*)seqv;

  extern __shared__ float lds[];
  float4* wv4  = (float4*)lds;            // [32][128] w_hh slice, swizzled
  float*  hst  = lds + 4 * 32 * 128;      // 16384 f: x/h stage, then red+gbuf
  float4* hst4 = (float4*)hst;
  float*  red  = hst;                     // [4][32 r *33 + b] overlay
  float*  gbuf = hst + 4224;              // [32 r *33 + b]
  float*  bsum = hst + 16384;             // [32]

  for (int idx = tid; idx < 32 * 128; idx += NTH) {
    int r = idx >> 7, c4 = idx & 127;
    int grow = (r >> 3) * HIDDEN + u0 + (r & 7);
    wv4[r * 128 + (c4 ^ ((r >> 2) & 7))] =
        *(const float4*)(w_hh + (size_t)grow * HIDDEN + c4 * 4);
  }
  if (tid < 32) {
    int grow = (tid >> 3) * HIDDEN + u0 + (tid & 7);
    bsum[tid] = bi[grow] + bh[grow];
  }
  const int rr = tid & 7, bb = (tid >> 3) & 7, kc = tid >> 6;
  const float* wxg[4];
#pragma unroll
  for (int j = 0; j < 4; ++j) {
    int r = 4 * rr + j;
    int grow = (r >> 3) * HIDDEN + u0 + (r & 7);
    wxg[j] = w_ih + (size_t)grow * DIN;
  }
  const int chain = L * 2 + g;
  int* fl  = bars + chain * 64;         // own chain arrival flags
  int* ep  = bars + 512 + chain * 16;   // own chain epoch word
  int* ep0 = bars + 512 + g * 16;       // layer-0 epoch, same batch group
  float* hb = hbuf1 + (size_t)g * 2 * 32 * HIDDEN;

  float creg = 0.0f;                    // c-state: thread owns (blf, luf)
  const int blf = tid >> 3, luf = tid & 7;
  __syncthreads();

  for (int t = 0; t < TSTEPS; ++t) {
    // ---- x acquisition (L1: gated on layer-0 epoch, single-word poll) ----
    float4 xr[4];
    if (L == 0) {
#pragma unroll
      for (int n = 0; n < 4; ++n) {
        int idx = tid + n * NTH, b = idx >> 5, c4 = idx & 31;
        xr[n] = *(const float4*)(xin + ((size_t)(b0 + b) * TSTEPS + t) * 128 + c4 * 4);
      }
    } else {
      unsigned long long sp0 = __builtin_amdgcn_s_memrealtime();
      while (ld_ci(ep0) < t + 1) {
        if (__builtin_amdgcn_s_memrealtime() - sp0 > SPIN_LIMIT) break;
        __builtin_amdgcn_s_sleep(1);
      }
      cfence();
    }

    // ---- stage x into hst ----
    if (L == 0) {
#pragma unroll
      for (int n = 0; n < 4; ++n) {
        int idx = tid + n * NTH, b = idx >> 5, c4 = idx & 31;
        hst4[b * 32 + (c4 ^ ((b >> 1) & 7))] = xr[n];
      }
    } else if (SEQF32) {
#pragma unroll 8
      for (int n = 0; n < 64; ++n) {
        int idx = tid + n * NTH, b = idx >> 9, c = idx & 511;
        float v = ld_cc(seqf + ((size_t)(b0 + b) * TSTEPS + t) * HIDDEN + c);
        hst[swz(b, c)] = v;
      }
    } else {
#pragma unroll 8
      for (int n = 0; n < 32; ++n) {
        int idx = tid + n * NTH, b = idx >> 8, wi = idx & 255;
        unsigned v = ld_cu(sequ + ((size_t)(b0 + b) * TSTEPS + t) * 256 + wi);
        int c0 = wi * 2, base = swz(b, c0);
        hst[base] = b2f((unsigned short)v);
        hst[base + 1] = b2f((unsigned short)(v >> 16));
      }
    }
    __syncthreads();

    float acc[4][4];
#pragma unroll
    for (int j = 0; j < 4; ++j)
#pragma unroll
      for (int i = 0; i < 4; ++i) acc[j][i] = 0.0f;

    // ---- x-part: K = DIN, weights streamed from L2 ----
    if (L == 0) {
#pragma unroll
      for (int kk = 0; kk < 8; ++kk) {
        int k4 = kc * 8 + kk;
        float4 wq[4], xq[4];
#pragma unroll
        for (int j = 0; j < 4; ++j) wq[j] = *(const float4*)(wxg[j] + k4 * 4);
#pragma unroll
        for (int i = 0; i < 4; ++i) {
          int b = 4 * bb + i;
          xq[i] = hst4[b * 32 + (k4 ^ ((b >> 1) & 7))];
        }
#pragma unroll
        for (int j = 0; j < 4; ++j)
#pragma unroll
          for (int i = 0; i < 4; ++i) fma4(acc[j][i], wq[j], xq[i]);
      }
    } else {
#pragma unroll 4
      for (int kk = 0; kk < 32; ++kk) {
        int k4 = kc * 32 + kk;
        float4 wq[4], xq[4];
#pragma unroll
        for (int j = 0; j < 4; ++j) wq[j] = *(const float4*)(wxg[j] + k4 * 4);
#pragma unroll
        for (int i = 0; i < 4; ++i) {
          int b = 4 * bb + i;
          xq[i] = hst4[b * 128 + (k4 ^ ((b >> 1) & 7))];
        }
#pragma unroll
        for (int j = 0; j < 4; ++j)
#pragma unroll
          for (int i = 0; i < 4; ++i) fma4(acc[j][i], wq[j], xq[i]);
      }
    }

    // ---- own-chain wait (h(t-1) complete), hidden under x-part above ----
    if (t > 0) {
      unsigned long long sp0 = __builtin_amdgcn_s_memrealtime();
      while (ld_ci(ep) < t) {
        if (__builtin_amdgcn_s_memrealtime() - sp0 > SPIN_LIMIT) break;
        __builtin_amdgcn_s_sleep(1);
      }
      cfence();
    }
    __syncthreads();   // x reads done before h overwrites stage

    // ---- stage h(t-1) into hst (L0: from seq; L1: from hbuf) ----
    if (t == 0) {
#pragma unroll 8
      for (int n = 0; n < 64; ++n) hst[tid + n * NTH] = 0.0f;
    } else if (L == 0) {
      if (SEQF32) {
#pragma unroll 8
        for (int n = 0; n < 64; ++n) {
          int idx = tid + n * NTH, b = idx >> 9, c = idx & 511;
          float v = ld_cc(seqf + ((size_t)(b0 + b) * TSTEPS + (t - 1)) * HIDDEN + c);
          hst[swz(b, c)] = v;
        }
      } else {
#pragma unroll 8
        for (int n = 0; n < 32; ++n) {
          int idx = tid + n * NTH, b = idx >> 8, wi = idx & 255;
          unsigned v = ld_cu(sequ + ((size_t)(b0 + b) * TSTEPS + (t - 1)) * 256 + wi);
          int c0 = wi * 2, base = swz(b, c0);
          hst[base] = b2f((unsigned short)v);
          hst[base + 1] = b2f((unsigned short)(v >> 16));
        }
      }
    } else {
      const float* hsrc = hb + (size_t)(t & 1) * (32 * HIDDEN);
#pragma unroll 8
      for (int n = 0; n < 64; ++n) {
        int idx = tid + n * NTH, b = idx >> 9, c = idx & 511;
        float v = ld_cc(hsrc + b * HIDDEN + c);
        hst[swz(b, c)] = v;
      }
    }
    __syncthreads();

    // ---- h-part: K = 512, w_hh from LDS ----
#pragma unroll 4
    for (int kk = 0; kk < 32; ++kk) {
      int k4 = kc * 32 + kk;
      float4 wq[4], hq[4];
#pragma unroll
      for (int j = 0; j < 4; ++j) wq[j] = wv4[(4 * rr + j) * 128 + (k4 ^ rr)];
#pragma unroll
      for (int i = 0; i < 4; ++i) {
        int b = 4 * bb + i;
        hq[i] = hst4[b * 128 + (k4 ^ ((b >> 1) & 7))];
      }
#pragma unroll
      for (int j = 0; j < 4; ++j)
#pragma unroll
        for (int i = 0; i < 4; ++i) fma4(acc[j][i], wq[j], hq[i]);
    }
    __syncthreads();   // h reads done before reduction overlay

    // ---- K-split reduction (4 partials) ----
#pragma unroll
    for (int j = 0; j < 4; ++j)
#pragma unroll
      for (int i = 0; i < 4; ++i)
        red[kc * 1056 + (4 * rr + j) * 33 + (4 * bb + i)] = acc[j][i];
    __syncthreads();
#pragma unroll
    for (int q = 0; q < 4; ++q) {
      int idx = tid + q * NTH, r = idx >> 5, b = idx & 31;
      float s = bsum[r];
#pragma unroll
      for (int k2 = 0; k2 < 4; ++k2) s += red[k2 * 1056 + r * 33 + b];
      gbuf[r * 33 + b] = s;
    }
    __syncthreads();

    // ---- gates: thread owns (blf, luf) ----
    {
      float gi = gbuf[(0  + luf) * 33 + blf];
      float gf = gbuf[(8  + luf) * 33 + blf];
      float gg = gbuf[(16 + luf) * 33 + blf];
      float go = gbuf[(24 + luf) * 33 + blf];
      float iv = sigm(gi), fv = sigm(gf), gv = tanh_fast(gg), ov = sigm(go);
      float c = fv * creg + iv * gv;
      creg = c;
      float hn = ov * tanh_fast(c);
      if (L == 0) {
        if (SEQF32) {
          st_cc(seqf + ((size_t)(b0 + blf) * TSTEPS + t) * HIDDEN + u0 + luf, hn);
        } else {
          float other = __shfl_xor(hn, 1);
          if ((luf & 1) == 0) {
            bf16 lo = __float2bfloat16(hn), hi = __float2bfloat16(other);
            unsigned pv = (unsigned)(*(unsigned short*)&lo) |
                          ((unsigned)(*(unsigned short*)&hi) << 16);
            st_cu(sequ + ((size_t)(b0 + blf) * TSTEPS + t) * 256 + ((u0 + luf) >> 1), pv);
          }
        }
      } else {
        st_cc(hb + (size_t)((t + 1) & 1) * (32 * HIDDEN) + blf * HIDDEN + u0 + luf, hn);
      }
    }
    __syncthreads();   // drains vmcnt: h stores visible before flag
    if (tid == 0) st_ci(&fl[w], t + 1);
    cfence();
    // ---- gatherer (w==0): collect 64 flags, publish single epoch word ----
    if (w == 0 && tid < 64) {
      unsigned long long sp0 = __builtin_amdgcn_s_memrealtime();
      while (true) {
        int v = ld_ci(&fl[tid]);
        if (__all(v >= t + 1)) break;
        if (__builtin_amdgcn_s_memrealtime() - sp0 > SPIN_LIMIT) break;
        __builtin_amdgcn_s_sleep(1);
      }
      if (tid == 0) st_ci(ep, t + 1);
    }
  }
}

// ---------------------------------------------------------------------------
// FC: out[b][o] = dot(h2[b], fc_w[o]) + fc_b[o]. h2 = hbuf1[g][buf0][b&31].
// ---------------------------------------------------------------------------
__global__ __launch_bounds__(NTH, 1)
void fc_kernel(const float* __restrict__ hbuf1, const float* __restrict__ fcw,
               const float* __restrict__ fcb, float* __restrict__ out)
{
  extern __shared__ float lds[];
  float4* fw4 = (float4*)lds;          // [64][128] swizzled
  float4* h24 = fw4 + 64 * 128;        // [8][128]
  const int tid = threadIdx.x;
  const int bq  = blockIdx.x;

  for (int idx = tid; idx < 64 * 128; idx += NTH) {
    int o = idx >> 7, c4 = idx & 127;
    fw4[o * 128 + (c4 ^ (o & 7))] = *(const float4*)(fcw + (size_t)o * HIDDEN + c4 * 4);
  }
  for (int idx = tid; idx < 8 * 128; idx += NTH) {
    int b = idx >> 7, c4 = idx & 127;
    int bg = bq * 8 + b;
    const float* hp = hbuf1 + (size_t)(bg >> 5) * 2 * 32 * HIDDEN + (bg & 31) * HIDDEN;
    h24[b * 128 + c4] = *(const float4*)(hp + c4 * 4);
  }
  __syncthreads();

  const int o = tid & 63, bs = tid >> 6;
  float a0 = 0.f, a1 = 0.f;
  for (int c4 = 0; c4 < 128; ++c4) {
    float4 wv = fw4[o * 128 + (c4 ^ (o & 7))];
    float4 h0 = h24[(2 * bs) * 128 + c4];
    float4 h1 = h24[(2 * bs + 1) * 128 + c4];
    fma4(a0, wv, h0);
    fma4(a1, wv, h1);
  }
  const float bo = fcb[o];
  out[(size_t)(bq * 8 + 2 * bs) * 64 + o]     = a0 + bo;
  out[(size_t)(bq * 8 + 2 * bs + 1) * 64 + o] = a1 + bo;
}

__global__ void init_ws(float* hbuf1, int* bars)
{
  int i = blockIdx.x * blockDim.x + threadIdx.x;
  if (i < 2 * 2 * 32 * HIDDEN) hbuf1[i] = 0.0f;   // 65536 floats
  if (i < 1024) bars[i] = 0;
}

// ---------------------------------------------------------------------------
extern "C" void kernel_launch(void* const* d_in, const int* in_sizes, int n_in,
                              void* d_out, int out_size, void* d_ws, size_t ws_size,
                              hipStream_t stream)
{
  const float* x    = (const float*)d_in[0];
  const float* wih0 = (const float*)d_in[1];
  const float* whh0 = (const float*)d_in[2];
  const float* bih0 = (const float*)d_in[3];
  const float* bhh0 = (const float*)d_in[4];
  const float* wih1 = (const float*)d_in[5];
  const float* whh1 = (const float*)d_in[6];
  const float* bih1 = (const float*)d_in[7];
  const float* bhh1 = (const float*)d_in[8];
  const float* fcw  = (const float*)d_in[9];
  const float* fcb  = (const float*)d_in[10];
  float* out = (float*)d_out;

  // ws layout: bars 1024 int | hbuf1 65536 f | seq
  float* wsf   = (float*)d_ws;
  int*   bars  = (int*)d_ws;
  float* hbuf1 = wsf + 1024;
  void*  seqv  = (void*)(hbuf1 + 2 * 2 * 32 * HIDDEN);

  const size_t head_bytes = (size_t)(1024 + 65536) * 4;
  const size_t seq_f32    = (size_t)64 * TSTEPS * HIDDEN * 4;
  const bool f32seq = ws_size >= head_bytes + seq_f32;

  const size_t ldsS  = (size_t)(32 * 128) * 16 + (size_t)(16384 + 32) * 4;  // 131,200 B
  const size_t ldsfc = (size_t)(64 * 128 + 8 * 128) * 16;

  hipLaunchKernelGGL(init_ws, dim3(256), dim3(256), 0, stream, hbuf1, bars);

  if (f32seq) {
    auto* k = lstm2<1>;
    hipFuncSetAttribute((const void*)k, hipFuncAttributeMaxDynamicSharedMemorySize, (int)ldsS);
    void* args[] = { (void*)&x,
                     (void*)&wih0, (void*)&whh0, (void*)&bih0, (void*)&bhh0,
                     (void*)&wih1, (void*)&whh1, (void*)&bih1, (void*)&bhh1,
                     (void*)&hbuf1, (void*)&seqv, (void*)&bars };
    if (hipLaunchCooperativeKernel((const void*)k, dim3(256), dim3(NTH), args,
                                   (unsigned)ldsS, stream) != hipSuccess) {
      lstm2<1><<<dim3(256), dim3(NTH), ldsS, stream>>>(
          x, wih0, whh0, bih0, bhh0, wih1, whh1, bih1, bhh1, hbuf1, seqv, bars);
    }
  } else {
    auto* k = lstm2<0>;
    hipFuncSetAttribute((const void*)k, hipFuncAttributeMaxDynamicSharedMemorySize, (int)ldsS);
    void* args[] = { (void*)&x,
                     (void*)&wih0, (void*)&whh0, (void*)&bih0, (void*)&bhh0,
                     (void*)&wih1, (void*)&whh1, (void*)&bih1, (void*)&bhh1,
                     (void*)&hbuf1, (void*)&seqv, (void*)&bars };
    if (hipLaunchCooperativeKernel((const void*)k, dim3(256), dim3(NTH), args,
                                   (unsigned)ldsS, stream) != hipSuccess) {
      lstm2<0><<<dim3(256), dim3(NTH), ldsS, stream>>>(
          x, wih0, whh0, bih0, bhh0, wih1, whh1, bih1, bhh1, hbuf1, seqv, bars);
    }
  }

  hipFuncSetAttribute((const void*)fc_kernel, hipFuncAttributeMaxDynamicSharedMemorySize, (int)ldsfc);
  hipLaunchKernelGGL(fc_kernel, dim3(8), dim3(NTH), ldsfc, stream, hbuf1, fcw, fcb, out);
}

// Round 10
// 18539.633 us; speedup vs baseline: 2.9081x; 2.7312x over previous
//
#include <hip/hip_runtime.h>
#include <hip/hip_bf16.h>

// LSTM_19267223290530 — 2-layer LSTM (B=64,T=1024,IN=128,HID=512) + FC.
// Round 10: R5 (19.5ms, proven) + three surgical deltas:
//  1. GLOBAL deadline on all spins (R9's per-spin bails compounded to 8000s).
//  2. Epoch wait moved AFTER the x-part (barrier hop hides under x compute).
//  3. h exchange: 8x global_load_dwordx4 sc0 sc1 in ONE asm block with
//     internal vmcnt(0) (rule-18-safe), replacing 32 scalar agent loads.
// Topology/barrier/math identical to R5.

#define NTH 256
#define WPG 64      // workgroups per barrier group
#define NGRP 4      // batch groups
#define BPG 16      // batches per group
#define UPW 8       // hidden units per wg
#define RPW 32      // gate rows per wg (4*UPW)
#define HIDDEN 512
#define TSTEPS 1024
#define BATCH 64

// spin budget: ABSOLUTE deadline per kernel (~4s at 100MHz s_memrealtime).
#define SPIN_BUDGET 400000000ull

using bf16 = __hip_bfloat16;

__device__ __forceinline__ float b2fl(unsigned short s) {
  return __uint_as_float(((unsigned int)s) << 16);
}

template<typename T> struct Ld4;
template<> struct Ld4<float> {
  static __device__ __forceinline__ float4 go(const float* p) { return *(const float4*)p; }
};
template<> struct Ld4<bf16> {
  static __device__ __forceinline__ float4 go(const bf16* p) {
    ushort4 v = *(const ushort4*)p;
    return make_float4(b2fl(v.x), b2fl(v.y), b2fl(v.z), b2fl(v.w));
  }
};

template<typename T> __device__ __forceinline__ T to_xout(float f);
template<> __device__ __forceinline__ float to_xout<float>(float f) { return f; }
template<> __device__ __forceinline__ bf16 to_xout<bf16>(float f) { return __float2bfloat16(f); }

__device__ __forceinline__ float sigm(float x) { return 1.0f / (1.0f + __expf(-x)); }
__device__ __forceinline__ float tanh_fast(float x) {
  float ax = fabsf(x);
  float e2 = __expf(2.0f * ax);
  float t  = 1.0f - 2.0f / (e2 + 1.0f);
  return copysignf(t, x);
}
__device__ __forceinline__ void fma4(float& a, const float4 w, const float4 h) {
  a = fmaf(w.x, h.x, a);
  a = fmaf(w.y, h.y, a);
  a = fmaf(w.z, h.z, a);
  a = fmaf(w.w, h.w, a);
}

// coherent (device-visible, no cache maintenance) scalar ops — R4-proven
__device__ __forceinline__ void st_cc(float* p, float v) {
  __hip_atomic_store(p, v, __ATOMIC_RELAXED, __HIP_MEMORY_SCOPE_AGENT);
}
__device__ __forceinline__ void st_ci(int* p, int v) {
  __hip_atomic_store(p, v, __ATOMIC_RELAXED, __HIP_MEMORY_SCOPE_AGENT);
}
__device__ __forceinline__ int ld_ci(const int* p) {
  return __hip_atomic_load((int*)p, __ATOMIC_RELAXED, __HIP_MEMORY_SCOPE_AGENT);
}
__device__ __forceinline__ void cfence() { asm volatile("" ::: "memory"); }

// 8x coherent dwordx4 load, single asm block, wait INSIDE the block so the
// outputs are valid on exit (rule 18: compiler cannot reorder consumers in).
__device__ __forceinline__ void ld_h8(const float4* base, int tid, float4 hv[8]) {
  const float4* p0 = base + tid;
  const float4* p1 = base + tid + 1 * NTH;
  const float4* p2 = base + tid + 2 * NTH;
  const float4* p3 = base + tid + 3 * NTH;
  const float4* p4 = base + tid + 4 * NTH;
  const float4* p5 = base + tid + 5 * NTH;
  const float4* p6 = base + tid + 6 * NTH;
  const float4* p7 = base + tid + 7 * NTH;
  asm volatile(
      "global_load_dwordx4 %0, %8, off sc0 sc1\n\t"
      "global_load_dwordx4 %1, %9, off sc0 sc1\n\t"
      "global_load_dwordx4 %2, %10, off sc0 sc1\n\t"
      "global_load_dwordx4 %3, %11, off sc0 sc1\n\t"
      "global_load_dwordx4 %4, %12, off sc0 sc1\n\t"
      "global_load_dwordx4 %5, %13, off sc0 sc1\n\t"
      "global_load_dwordx4 %6, %14, off sc0 sc1\n\t"
      "global_load_dwordx4 %7, %15, off sc0 sc1\n\t"
      "s_waitcnt vmcnt(0)"
      : "=&v"(hv[0]), "=&v"(hv[1]), "=&v"(hv[2]), "=&v"(hv[3]),
        "=&v"(hv[4]), "=&v"(hv[5]), "=&v"(hv[6]), "=&v"(hv[7])
      : "v"(p0), "v"(p1), "v"(p2), "v"(p3), "v"(p4), "v"(p5), "v"(p6), "v"(p7)
      : "memory");
  __builtin_amdgcn_sched_barrier(0);
}

// ---------------------------------------------------------------------------
// Persistent LSTM scan (R5 topology). grid = 256 wgs x 256 thr, 1 wg/CU.
// group g = bid&3 owns batches [16g,16g+16); wg w = bid>>2 owns units [8w,8w+8).
// Barrier: flags[g*64+w] -> gatherer (w==0 wave0) -> epoch word -> broadcast.
// ---------------------------------------------------------------------------
template<int D_IN, bool WRITE_SEQ, typename XIN, typename XOUT>
__global__ __launch_bounds__(NTH, 1)
void lstm_scan(const XIN* __restrict__ xin,
               const float* __restrict__ w_ih,
               const float* __restrict__ w_hh,
               const float* __restrict__ b_ih,
               const float* __restrict__ b_hh,
               float* __restrict__ hbuf,        // [2][64][512]
               XOUT* __restrict__ seqout,       // [64][1024][512] (WRITE_SEQ)
               int* __restrict__ barbase)       // 512 ints for this layer
{
  constexpr int D4 = D_IN / 4;
  constexpr bool XW_LDS = (D_IN <= 128);        // layer0: w_ih fits LDS
  constexpr int S4 = 128 + (XW_LDS ? D4 : 0);   // wv row stride (float4)
  constexpr int XC = D_IN / 8;                  // x K-chunk per kc
  constexpr int LD4 = (D_IN == 128) ? 5 : 7;
  constexpr int XPT = (BPG * D4) / NTH;         // x float4 per thread (L0:2, L1:8)

  extern __shared__ float lds[];
  float4* wv4 = (float4*)lds;                   // [RPW][S4] swizzled
  float4* hs4 = wv4 + RPW * S4;                 // [BPG][128] swizzled
  float4* xs4 = hs4 + BPG * 128;                // [BPG][D4]  swizzled
  float*  red = (float*)(xs4 + BPG * D4);       // [8][512]; row0 doubles as gbuf
  float*  bsum = red + 8 * 512;                 // [32]
  float*  cst  = bsum + RPW;                    // [16][8] c-state

  const int tid = threadIdx.x;
  const int bid = blockIdx.x;
  const int g   = bid & 3;
  const int w   = bid >> 2;
  const int b0g = g * BPG;
  const int u0  = w * UPW;
  int* flags = barbase + g * 64;                // arrival flags, monotone
  int* epoch = barbase + 320 + g * 16;          // single release word per group

  const unsigned long long deadline =
      __builtin_amdgcn_s_memrealtime() + SPIN_BUDGET;   // GLOBAL bail

  // ---- weights -> LDS (XOR swizzle) ----
  for (int idx = tid; idx < RPW * S4; idx += NTH) {
    int r  = idx / S4;
    int c4 = idx - r * S4;
    int swz = (r >> 2) & 7;
    int grow = ((r >> 3) * HIDDEN) + u0 + (r & 7);
    if (c4 < 128) {
      float4 v = *(const float4*)(w_hh + (size_t)grow * HIDDEN + c4 * 4);
      wv4[r * S4 + (c4 ^ swz)] = v;
    } else {
      int c4x = c4 - 128;
      float4 v = *(const float4*)(w_ih + (size_t)grow * D_IN + c4x * 4);
      wv4[r * S4 + 128 + (c4x ^ swz)] = v;
    }
  }
  if (tid < RPW) {
    int grow = ((tid >> 3) * HIDDEN) + u0 + (tid & 7);
    bsum[tid] = b_ih[grow] + b_hh[grow];
  }
  if (tid < UPW * BPG) cst[tid] = 0.0f;

  const int rr = tid & 7;          // row quad
  const int bb = (tid >> 3) & 3;   // batch quad
  const int kc = tid >> 5;         // K chunk 0..7

  const float* wxg[4];             // layer1: x-weight rows stream from L2
  if (!XW_LDS) {
#pragma unroll
    for (int j = 0; j < 4; ++j) {
      int r = 4 * rr + j;
      int grow = ((r >> 3) * HIDDEN) + u0 + (r & 7);
      wxg[j] = w_ih + (size_t)grow * D_IN;
    }
  }
  __syncthreads();

  for (int t = 0; t < TSTEPS; ++t) {
    const float* hsrc = hbuf + (size_t)(t & 1) * (BATCH * HIDDEN);
    float*       hdst = hbuf + (size_t)((t + 1) & 1) * (BATCH * HIDDEN);

    // ---- stage x[t] -> LDS (barrier-independent: input / prev-kernel seq) ----
#pragma unroll
    for (int n = 0; n < XPT; ++n) {
      int idx = tid + n * NTH;
      int b = idx >> LD4, c4 = idx & (D4 - 1);
      float4 v = Ld4<XIN>::go(xin + ((size_t)(b0g + b) * TSTEPS + t) * D_IN + c4 * 4);
      xs4[b * D4 + (c4 ^ (b >> 2))] = v;
    }
    __syncthreads();   // xs4 ready

    float acc[4][4];
#pragma unroll
    for (int j = 0; j < 4; ++j)
#pragma unroll
      for (int i = 0; i < 4; ++i) acc[j][i] = 0.0f;

    // ---- X-PART first (xs4 + weights only; epoch hop hides under this) ----
#pragma unroll 2
    for (int kk = 0; kk < XC / 4; ++kk) {
      const int k4 = kc * (XC / 4) + kk;
      float4 wq[4], xq[4];
      if constexpr (XW_LDS) {
#pragma unroll
        for (int j = 0; j < 4; ++j) wq[j] = wv4[(4 * rr + j) * S4 + 128 + (k4 ^ rr)];
      } else {
#pragma unroll
        for (int j = 0; j < 4; ++j) wq[j] = *(const float4*)(wxg[j] + k4 * 4);
      }
#pragma unroll
      for (int i = 0; i < 4; ++i) xq[i] = xs4[(4 * bb + i) * D4 + (k4 ^ bb)];
#pragma unroll
      for (int j = 0; j < 4; ++j)
#pragma unroll
        for (int i = 0; i < 4; ++i) fma4(acc[j][i], wq[j], xq[i]);
    }

    // ---- wait for h(t-1): all threads poll ONE epoch word (broadcast) ----
    if (t > 0) {
      while (ld_ci(epoch) < t) {
        if (__builtin_amdgcn_s_memrealtime() > deadline) break;  // bounded bail
        __builtin_amdgcn_s_sleep(1);
      }
      cfence();   // forbid hoisting the h loads above the poll
    }

    // ---- h(t-1): 8x dwordx4 coherent load (one asm block, waits inside) ----
    {
      float4 hv[8];
      ld_h8((const float4*)(hsrc + (size_t)b0g * HIDDEN), tid, hv);
#pragma unroll
      for (int n = 0; n < 8; ++n) {
        int idx = tid + n * NTH;
        int b = idx >> 7, c4 = idx & 127;
        hs4[b * 128 + (c4 ^ (b >> 2))] = hv[n];
      }
    }
    __syncthreads();   // hs4 ready

    // ---- H-PART: K chunk [kc*64, kc*64+64) ----
#pragma unroll 4
    for (int kk = 0; kk < 16; ++kk) {
      const int k4 = kc * 16 + kk;
      float4 wq[4], hq[4];
#pragma unroll
      for (int j = 0; j < 4; ++j) wq[j] = wv4[(4 * rr + j) * S4 + (k4 ^ rr)];
#pragma unroll
      for (int i = 0; i < 4; ++i) hq[i] = hs4[(4 * bb + i) * 128 + (k4 ^ bb)];
#pragma unroll
      for (int j = 0; j < 4; ++j)
#pragma unroll
        for (int i = 0; i < 4; ++i) fma4(acc[j][i], wq[j], hq[i]);
    }

    // ---- K-split reduction ----
#pragma unroll
    for (int j = 0; j < 4; ++j)
#pragma unroll
      for (int i = 0; i < 4; ++i)
        red[kc * 512 + (4 * rr + j) * 16 + 4 * bb + i] = acc[j][i];
    __syncthreads();
    {
      const int a0 = tid, a1 = tid + 256;
      float s0 = bsum[a0 >> 4], s1 = bsum[a1 >> 4];
#pragma unroll
      for (int k2 = 0; k2 < 8; ++k2) {
        s0 += red[k2 * 512 + a0];
        s1 += red[k2 * 512 + a1];
      }
      red[a0] = s0;   // gbuf alias: only this thread reads/writes column a0/a1
      red[a1] = s1;
    }
    __syncthreads();

    // ---- gates / state update ----
    if (tid < UPW * BPG) {
      const int lu = tid & 7, bl = tid >> 3;
      float gi = red[(0  + lu) * 16 + bl];
      float gf = red[(8  + lu) * 16 + bl];
      float gg = red[(16 + lu) * 16 + bl];
      float go = red[(24 + lu) * 16 + bl];
      float iv = sigm(gi), fv = sigm(gf), gv = tanh_fast(gg), ov = sigm(go);
      float c = fv * cst[tid] + iv * gv;
      cst[tid] = c;
      float hn = ov * tanh_fast(c);
      const int b = b0g + bl, u = u0 + lu;
      st_cc(hdst + (size_t)b * HIDDEN + u, hn);       // coherent write-through
      if constexpr (WRITE_SEQ)
        seqout[((size_t)b * TSTEPS + t) * HIDDEN + u] = to_xout<XOUT>(hn);
    }

    // ---- arrival + release (R5 two-hop barrier, unchanged) ----
    __syncthreads();   // drains vmcnt: h stores device-visible before flag
    if (tid == 0)
      st_ci(&flags[w], t + 1);
    cfence();
    if (w == 0 && tid < WPG) {   // wg0 wave0: gather arrivals, publish epoch
      while (true) {
        int v = ld_ci(&flags[tid]);
        if (__all(v >= t + 1)) break;
        if (__builtin_amdgcn_s_memrealtime() > deadline) break;  // bounded bail
        __builtin_amdgcn_s_sleep(1);
      }
      if (tid == 0) st_ci(epoch, t + 1);
    }
    // no trailing __syncthreads: LDS reuse safe (pre-flag sync covers reads).
  }
}

// ---------------------------------------------------------------------------
// FC: out[b][o] = dot(h2[b], fc_w[o]) + fc_b[o].  grid 8, block 256.
// ---------------------------------------------------------------------------
__global__ __launch_bounds__(NTH, 1)
void fc_kernel(const float* __restrict__ h2, const float* __restrict__ fcw,
               const float* __restrict__ fcb, float* __restrict__ out)
{
  extern __shared__ float lds[];
  float4* fw4 = (float4*)lds;          // [64][128] swizzled
  float4* h24 = fw4 + 64 * 128;        // [8][128]
  const int tid = threadIdx.x;
  const int bq  = blockIdx.x;

  for (int idx = tid; idx < 64 * 128; idx += NTH) {
    int o = idx >> 7, c4 = idx & 127;
    fw4[o * 128 + (c4 ^ (o & 7))] = *(const float4*)(fcw + (size_t)o * HIDDEN + c4 * 4);
  }
  for (int idx = tid; idx < 8 * 128; idx += NTH) {
    int b = idx >> 7, c4 = idx & 127;
    h24[b * 128 + c4] = *(const float4*)(h2 + (size_t)(bq * 8 + b) * HIDDEN + c4 * 4);
  }
  __syncthreads();

  const int o = tid & 63, bs = tid >> 6;
  float a0 = 0.f, a1 = 0.f;
  for (int c4 = 0; c4 < 128; ++c4) {
    float4 wv = fw4[o * 128 + (c4 ^ (o & 7))];
    float4 h0 = h24[(2 * bs) * 128 + c4];
    float4 h1 = h24[(2 * bs + 1) * 128 + c4];
    fma4(a0, wv, h0);
    fma4(a1, wv, h1);
  }
  const float bo = fcb[o];
  out[(size_t)(bq * 8 + 2 * bs) * 64 + o]     = a0 + bo;
  out[(size_t)(bq * 8 + 2 * bs + 1) * 64 + o] = a1 + bo;
}

__global__ void init_ws(float* hbuf0, float* hbuf1, int* bars)
{
  int i = blockIdx.x * blockDim.x + threadIdx.x;
  if (i < 2 * BATCH * HIDDEN) { hbuf0[i] = 0.f; hbuf1[i] = 0.f; }
  if (i < 1024) bars[i] = 0;
}

// ---------------------------------------------------------------------------
extern "C" void kernel_launch(void* const* d_in, const int* in_sizes, int n_in,
                              void* d_out, int out_size, void* d_ws, size_t ws_size,
                              hipStream_t stream)
{
  const float* x    = (const float*)d_in[0];
  const float* wih0 = (const float*)d_in[1];
  const float* whh0 = (const float*)d_in[2];
  const float* bih0 = (const float*)d_in[3];
  const float* bhh0 = (const float*)d_in[4];
  const float* wih1 = (const float*)d_in[5];
  const float* whh1 = (const float*)d_in[6];
  const float* bih1 = (const float*)d_in[7];
  const float* bhh1 = (const float*)d_in[8];
  const float* fcw  = (const float*)d_in[9];
  const float* fcb  = (const float*)d_in[10];
  float* out = (float*)d_out;

  // ws layout: bars 1024 int | hbuf0 | hbuf1 | seq
  float* wsf   = (float*)d_ws;
  int*   bars  = (int*)d_ws;                 // 1024 ints: L0 [0..511], L1 [512..1023]
  float* hbuf0 = wsf + 1024;
  float* hbuf1 = hbuf0 + 2 * BATCH * HIDDEN;
  float* seqf  = hbuf1 + 2 * BATCH * HIDDEN;
  const size_t seq_elems = (size_t)BATCH * TSTEPS * HIDDEN;
  const size_t base_bytes = (1024 + 4 * BATCH * HIDDEN) * 4;
  const bool f32seq = ws_size >= base_bytes + seq_elems * 4;

  // LDS sizes (bytes) — identical to R5
  const size_t lds0  = (size_t)((RPW * 160 + BPG * 128 + BPG * 32) * 4 + 8 * 512 + RPW + 128) * 4;
  const size_t lds1  = (size_t)((RPW * 128 + BPG * 128 + BPG * 128) * 4 + 8 * 512 + RPW + 128) * 4;
  const size_t ldsfc = (size_t)(64 * 128 + 8 * 128) * 16;

  hipLaunchKernelGGL(init_ws, dim3(256), dim3(256), 0, stream, hbuf0, hbuf1, bars);

  int* bar0 = bars;
  int* bar1 = bars + 512;
  float* dummy = nullptr;

  if (f32seq) {
    auto* k0 = lstm_scan<128, true,  float, float>;
    auto* k1 = lstm_scan<512, false, float, float>;
    hipFuncSetAttribute((const void*)k0, hipFuncAttributeMaxDynamicSharedMemorySize, (int)lds0);
    hipFuncSetAttribute((const void*)k1, hipFuncAttributeMaxDynamicSharedMemorySize, (int)lds1);
    float* seqp = seqf;
    void* a0[] = { (void*)&x,    (void*)&wih0, (void*)&whh0, (void*)&bih0, (void*)&bhh0,
                   (void*)&hbuf0, (void*)&seqp, (void*)&bar0 };
    if (hipLaunchCooperativeKernel((const void*)k0, dim3(NGRP * WPG), dim3(NTH), a0,
                                   (unsigned)lds0, stream) != hipSuccess) {
      lstm_scan<128, true, float, float><<<dim3(NGRP * WPG), dim3(NTH), lds0, stream>>>(
          x, wih0, whh0, bih0, bhh0, hbuf0, seqp, bar0);
    }
    const float* seqc = seqf;
    void* a1[] = { (void*)&seqc, (void*)&wih1, (void*)&whh1, (void*)&bih1, (void*)&bhh1,
                   (void*)&hbuf1, (void*)&dummy, (void*)&bar1 };
    if (hipLaunchCooperativeKernel((const void*)k1, dim3(NGRP * WPG), dim3(NTH), a1,
                                   (unsigned)lds1, stream) != hipSuccess) {
      lstm_scan<512, false, float, float><<<dim3(NGRP * WPG), dim3(NTH), lds1, stream>>>(
          seqc, wih1, whh1, bih1, bhh1, hbuf1, dummy, bar1);
    }
  } else {
    auto* k0 = lstm_scan<128, true,  float, bf16>;
    auto* k1 = lstm_scan<512, false, bf16, float>;
    hipFuncSetAttribute((const void*)k0, hipFuncAttributeMaxDynamicSharedMemorySize, (int)lds0);
    hipFuncSetAttribute((const void*)k1, hipFuncAttributeMaxDynamicSharedMemorySize, (int)lds1);
    bf16* seqb = (bf16*)seqf;
    void* a0[] = { (void*)&x,    (void*)&wih0, (void*)&whh0, (void*)&bih0, (void*)&bhh0,
                   (void*)&hbuf0, (void*)&seqb, (void*)&bar0 };
    if (hipLaunchCooperativeKernel((const void*)k0, dim3(NGRP * WPG), dim3(NTH), a0,
                                   (unsigned)lds0, stream) != hipSuccess) {
      lstm_scan<128, true, float, bf16><<<dim3(NGRP * WPG), dim3(NTH), lds0, stream>>>(
          x, wih0, whh0, bih0, bhh0, hbuf0, seqb, bar0);
    }
    const bf16* seqc = (const bf16*)seqf;
    void* a1[] = { (void*)&seqc, (void*)&wih1, (void*)&whh1, (void*)&bih1, (void*)&bhh1,
                   (void*)&hbuf1, (void*)&dummy, (void*)&bar1 };
    if (hipLaunchCooperativeKernel((const void*)k1, dim3(NGRP * WPG), dim3(NTH), a1,
                                   (unsigned)lds1, stream) != hipSuccess) {
      lstm_scan<512, false, bf16, float><<<dim3(NGRP * WPG), dim3(NTH), lds1, stream>>>(
          seqc, wih1, whh1, bih1, bhh1, hbuf1, dummy, bar1);
    }
  }

  hipFuncSetAttribute((const void*)fc_kernel, hipFuncAttributeMaxDynamicSharedMemorySize, (int)ldsfc);
  hipLaunchKernelGGL(fc_kernel, dim3(8), dim3(NTH), ldsfc, stream, hbuf1, fcw, fcb, out);
}